// Round 1
// 447.865 us; speedup vs baseline: 1.0330x; 1.0330x over previous
//
#include <hip/hip_runtime.h>
#include <hip/hip_bf16.h>

#define K_IN 2624     // 2048 + 512 + 64
#define NSTEP 82      // K-steps of 32 (prep granularity == pipeline chunk)
#define NCHUNK 82     // lstm pipeline chunks of 32 k

typedef __attribute__((ext_vector_type(8))) short short8;
typedef __attribute__((ext_vector_type(4))) float float4_t;

__device__ __forceinline__ short f2bf(float f) {
    union { __hip_bfloat16 b; short s; } u;
    u.b = __float2bfloat16(f);
    return u.s;
}

__device__ __forceinline__ float sigmoid_fast(float x) {
    return 1.f / (1.f + __expf(-x));
}

__device__ __forceinline__ float tanh_fast(float x) {
    float e = __expf(-2.f * fabsf(x));
    float t = (1.f - e) / (1.f + e);
    return copysignf(t, x);
}

// global -> LDS async DMA, 16 B/lane (global_load_lds_dwordx4).
// LDS dest is wave-uniform base (HW adds lane*16); global src is per-lane.
__device__ __forceinline__ void async16(const void* g, void* l) {
    __builtin_amdgcn_global_load_lds(
        (__attribute__((address_space(1))) void*)g,
        (__attribute__((address_space(3))) void*)l, 16, 0, 0);
}

// ---------------------------------------------------------------------------
// prep: pack fused weight [Wi;Wh] (K_IN x 256, fp32, k-major) into
// MFMA-B-fragment order, bf16 (unchanged from previous round):
//   Wt2[kstep s][nb][lane][8elem]: lane l holds B[k=s*32+(l>>4)*8+j][n=nb*16+(l&15)]
// Also bsum[n] = bi[n]+bh[n].
// ---------------------------------------------------------------------------
__global__ void prep_kernel(const float* __restrict__ Wi, const float* __restrict__ bi,
                            const float* __restrict__ Wh, const float* __restrict__ bh,
                            short* __restrict__ Wt2, float* __restrict__ bsum) {
    __shared__ short tile[32][264];   // +8 pad
    const int t = threadIdx.x;
    const int kb = blockIdx.x;
    const int k0 = kb * 32;

#pragma unroll 8
    for (int j = 0; j < 32; ++j) {
        int k = k0 + j;
        float v = (k < 2560) ? Wi[(size_t)k * 256 + t]
                             : Wh[(size_t)(k - 2560) * 256 + t];
        tile[j][t] = f2bf(v);
    }
    if (kb == 0) bsum[t] = bi[t] + bh[t];
    __syncthreads();

#pragma unroll
    for (int c = 0; c < 4; ++c) {
        int idx = c * 256 + t;          // 0..1023 = nb*64 + lane
        int lane = idx & 63;
        int nb = idx >> 6;
        int n = nb * 16 + (lane & 15);
        int j0 = (lane >> 4) * 8;
        short8 v;
#pragma unroll
        for (int j = 0; j < 8; ++j) v[j] = tile[j0 + j][n];
        *reinterpret_cast<short8*>(Wt2 + (size_t)kb * 8192 + (size_t)idx * 8) = v;
    }
}

// ---------------------------------------------------------------------------
// Fused GEMM + LSTM, round 4: async global_load_lds pipeline.
// 512 blocks x 256 threads (4 waves, 2 blocks/CU). Wave w owns 16 batch rows
// (bm*64 + w*16) x all 256 gate cols; acc = 16 x f32x4 = 64 VGPR.
// Per 32-k chunk each wave issues 6 global_load_lds (4 B + 2 A) into ring-2
// LDS buffers; raw s_barrier + counted vmcnt(6) keeps the next chunk's loads
// in flight across the barrier (never vmcnt(0) in steady state).
// A tile is XOR-swizzled (pre-swizzled SOURCE address, linear DMA dest,
// swizzled ds_read) for bank-balanced b128 frag reads.
// Epilogue is fully in-register: gates i,f,g,o of col n live in the same
// lane (acc[nb0], acc[nb0+4], acc[nb0+8], acc[nb0+12]); bias pre-loaded as
// MFMA C-in; out-projection via 4x shfl_xor over the 16-lane row group.
// ---------------------------------------------------------------------------
__global__ __launch_bounds__(256, 2)
void lstm_kernel(const float* __restrict__ state, const float* __restrict__ action,
                 const float* __restrict__ hidden, const float* __restrict__ cell,
                 const short* __restrict__ Wt2, const float* __restrict__ bsum,
                 const float* __restrict__ Wo, const float* __restrict__ bo,
                 float* __restrict__ out, int Brows) {
    // LDS: A ring2 [2][64 rows][128 B, 16B-groups XOR-swizzled] = 16 KB
    //      B ring2 [2][16 KB chunk, frag-linear]                = 32 KB
    __shared__ __align__(16) char smem[49152];
    char* const sA = smem;
    char* const sB = smem + 16384;

    const int t = threadIdx.x;
    const int w = t >> 6;
    const int l = t & 63;
    const int lr = l & 15;
    const int q = l >> 4;
    const int bm = blockIdx.x;

    // ---- A staging: wave w stages its own 16 rows per chunk via 2 DMA
    // insts (1 KB each = 8 rows x 128 B). Swizzle: LDS[row][g] holds
    // global[row][g ^ (row&7)] (16B groups) -> achieved by swizzling the
    // per-lane SOURCE address while the DMA dest stays linear (rule #21).
    const int rsub = l >> 3;               // row within the 8-row group
    const int scol = (l & 7) ^ rsub;       // pre-swizzled source 16B-group
    const char* aSrc[2];
    auto setA = [&](const float* p, int strideF) {
#pragma unroll
        for (int i = 0; i < 2; ++i) {
            size_t grow = (size_t)bm * 64 + w * 16 + i * 8 + rsub;
            aSrc[i] = (const char*)(p + grow * (size_t)strideF) + scol * 16;
        }
    };

    auto issueAB = [&](int buf, const char* bS) {
#pragma unroll
        for (int j = 0; j < 4; ++j)
            async16(bS + j * 1024, sB + buf * 16384 + (w * 4 + j) * 1024);
#pragma unroll
        for (int i = 0; i < 2; ++i) {
            async16(aSrc[i], sA + buf * 8192 + (w * 16 + i * 8) * 128);
            aSrc[i] += 128;   // next 32-k chunk within the same input buffer
        }
    };

    // accumulators preloaded with the fused gate bias (C-in of first MFMA)
    float4_t acc[16];
#pragma unroll
    for (int nb = 0; nb < 16; ++nb) acc[nb] = (float4_t)(bsum[nb * 16 + lr]);

    // prologue: chunks 0 and 1 in flight (12 outstanding loads/wave)
    setA(state, 2048);
    const char* bS0 = (const char*)Wt2 + (w * 4) * 1024 + l * 16;
    issueAB(0, bS0);
    issueAB(1, bS0 + 16384);
    const char* bSn = bS0 + 2 * 16384;

    const char* const sAb = sA + (w * 16 + lr) * 128;
    const char* const sBb = sB + l * 16;
    const int g0 = (2 * q) ^ (lr & 7);       // swizzled group of floats q*8..+3
    const int g1 = (2 * q + 1) ^ (lr & 7);   // swizzled group of floats q*8+4..+7

    auto compute = [&](int buf) {
        const char* bufA = sAb + buf * 8192;
        const char* bufB = sBb + buf * 16384;
        float4_t lo = *(const float4_t*)(bufA + g0 * 16);
        float4_t hi = *(const float4_t*)(bufA + g1 * 16);
        short8 a;
        a[0] = f2bf(lo[0]); a[1] = f2bf(lo[1]); a[2] = f2bf(lo[2]); a[3] = f2bf(lo[3]);
        a[4] = f2bf(hi[0]); a[5] = f2bf(hi[1]); a[6] = f2bf(hi[2]); a[7] = f2bf(hi[3]);
#pragma unroll
        for (int nb = 0; nb < 16; ++nb) {
            short8 b = *(const short8*)(bufB + nb * 1024);
            acc[nb] = __builtin_amdgcn_mfma_f32_16x16x32_bf16(a, b, acc[nb], 0, 0, 0);
        }
    };

    for (int k = 0; k < NCHUNK - 1; ++k) {
        // chunk k must be landed; chunk k+1's 6 loads stay in flight
        asm volatile("s_waitcnt vmcnt(6)" ::: "memory");
        __builtin_amdgcn_s_barrier();         // all waves' chunk-k data visible
        asm volatile("" ::: "memory");        // pin ds_reads after the barrier
        compute(k & 1);
        asm volatile("" ::: "memory");        // pin ds_reads before the barrier
        __builtin_amdgcn_s_barrier();         // all waves done reading buf k&1
        asm volatile("" ::: "memory");        // pin DMA issue after the barrier
        const int kk = k + 2;
        if (kk < NCHUNK) {
            if (kk == 64) setA(action, 512);  // state chunks 0..63
            if (kk == 80) setA(hidden, 64);   // action 64..79, hidden 80..81
            issueAB(k & 1, bSn);
            bSn += 16384;
        }
    }
    // last chunk: nothing newer in flight -> full drain is free
    asm volatile("s_waitcnt vmcnt(0)" ::: "memory");
    __builtin_amdgcn_s_barrier();
    asm volatile("" ::: "memory");
    compute((NCHUNK - 1) & 1);

    // ---- LSTM epilogue, fully in-register ----
    // lane (q,lr): rows bm*64 + w*16 + q*4 + r (r=0..3), cols n = nb0*16+lr.
    const float bov = bo[0];
    float wo_[4];
#pragma unroll
    for (int nb0 = 0; nb0 < 4; ++nb0) wo_[nb0] = Wo[nb0 * 16 + lr];

    const size_t rowbase = (size_t)bm * 64 + w * 16 + q * 4;
    float* outH = out + Brows;
    float* outC = outH + (size_t)Brows * 64;

#pragma unroll
    for (int r = 0; r < 4; ++r) {
        const size_t grow = rowbase + r;
        float vpart = 0.f;
#pragma unroll
        for (int nb0 = 0; nb0 < 4; ++nb0) {
            const int n = nb0 * 16 + lr;
            const float i_t = sigmoid_fast(acc[nb0][r]);
            const float f_t = sigmoid_fast(acc[nb0 + 4][r]);
            const float g_t = tanh_fast(acc[nb0 + 8][r]);
            const float o_t = sigmoid_fast(acc[nb0 + 12][r]);
            const float c_t = f_t * cell[grow * 64 + n] + i_t * g_t;
            const float h_t = o_t * tanh_fast(c_t);
            outC[grow * 64 + n] = c_t;
            outH[grow * 64 + n] = h_t;
            vpart += h_t * wo_[nb0];
        }
        // reduce over the 16 lanes (lr) of this q-group
        vpart += __shfl_xor(vpart, 1);
        vpart += __shfl_xor(vpart, 2);
        vpart += __shfl_xor(vpart, 4);
        vpart += __shfl_xor(vpart, 8);
        if (lr == 0) out[grow] = tanh_fast(vpart + bov);
    }
}

extern "C" void kernel_launch(void* const* d_in, const int* in_sizes, int n_in,
                              void* d_out, int out_size, void* d_ws, size_t ws_size,
                              hipStream_t stream) {
    const float* state  = (const float*)d_in[0];
    const float* action = (const float*)d_in[1];
    const float* hidden = (const float*)d_in[2];
    const float* cell   = (const float*)d_in[3];
    const float* Wi     = (const float*)d_in[4];
    const float* bi     = (const float*)d_in[5];
    const float* Wh     = (const float*)d_in[6];
    const float* bh     = (const float*)d_in[7];
    const float* Wo     = (const float*)d_in[8];
    const float* bo     = (const float*)d_in[9];

    const int Brows = in_sizes[0] / 2048;   // 32768

    short* Wt2  = (short*)d_ws;                                    // 82*8192 bf16
    float* bsum = (float*)((char*)d_ws + (size_t)NSTEP * 8192 * sizeof(short));

    prep_kernel<<<NSTEP, 256, 0, stream>>>(Wi, bi, Wh, bh, Wt2, bsum);
    lstm_kernel<<<Brows / 64, 256, 0, stream>>>(state, action, hidden, cell,
                                                Wt2, bsum, Wo, bo, (float*)d_out, Brows);
}